// Round 3
// baseline (375.471 us; speedup 1.0000x reference)
//
#include <hip/hip_runtime.h>

// ODE_23390391894829: batched RK4 integration of constant-curvature rod.
// Reference quirks replicated:
//  - actions[:,3:6] are NEVER used (reference loop re-reads segment 0 at n=0).
//  - lengths for BOTH segments come from l = L0 + actions[:,0].
//  - segment 2 continues the same trajectory (autonomous ODE, constant u).
// Output: (2T, B, 14) fp32, out[t] = traj[min(t,L)] per segment.
//
// R2->R3: wave-synchronous LDS staging, ZERO barriers. __syncthreads forced
// a `s_waitcnt vmcnt(0)` store-drain every row (26x), serializing store
// completion with RK4 compute. Now each 64-lane wave stages only its own
// 64x14 floats in a private LDS slice; intra-wave LDS ops are in-order
// (lockstep wave), so no barrier is needed. Stores are fire-and-forget and
// overlap the next row's compute. Coalescing preserved: 16 B/lane,
// 1 KB-contiguous per wave store instruction.

#define C_L0 0.05f
#define C_D  0.0075f
#define C_DS 0.005f
#define NB   256   // block size; 4 waves of 64

__device__ __forceinline__ void ode_f(const float* __restrict__ y, float ux, float uy,
                                      float* __restrict__ d) {
    d[0] = y[5];
    d[1] = y[8];
    d[2] = y[11];
#pragma unroll
    for (int i = 0; i < 3; ++i) {
        float Ri0 = y[3 + 3 * i + 0];
        float Ri1 = y[3 + 3 * i + 1];
        float Ri2 = y[3 + 3 * i + 2];
        d[3 + 3 * i + 0] = -uy * Ri2;
        d[3 + 3 * i + 1] =  ux * Ri2;
        d[3 + 3 * i + 2] =  uy * Ri0 - ux * Ri1;
    }
}

__device__ __forceinline__ void rk4_step(float* __restrict__ y, float ux, float uy) {
    const float h = C_DS;
    float k1[12], k2[12], k3[12], k4[12], t[12];
    ode_f(y, ux, uy, k1);
#pragma unroll
    for (int i = 0; i < 12; ++i) t[i] = y[i] + (0.5f * h) * k1[i];
    ode_f(t, ux, uy, k2);
#pragma unroll
    for (int i = 0; i < 12; ++i) t[i] = y[i] + (0.5f * h) * k2[i];
    ode_f(t, ux, uy, k3);
#pragma unroll
    for (int i = 0; i < 12; ++i) t[i] = y[i] + h * k3[i];
    ode_f(t, ux, uy, k4);
    const float c = h / 6.0f;
#pragma unroll
    for (int i = 0; i < 12; ++i)
        y[i] = y[i] + c * (k1[i] + 2.0f * k2[i] + 2.0f * k3[i] + k4[i]);
}

__global__ void __launch_bounds__(NB)
ode_kernel(const float* __restrict__ act, float* __restrict__ out, int B, int T) {
    // One private 64x14-float slice per wave; intra-wave in-order LDS pipe
    // means write(row t+1) cannot bypass read(row t) -> single buffer, no sync.
    __shared__ float lds[NB * 14];   // 14336 B

    const int tid  = threadIdx.x;
    const int lane = tid & 63;
    const int wv   = tid >> 6;
    const int b    = blockIdx.x * NB + tid;   // B % NB == 0

    const float a0 = act[b * 6 + 0];
    const float a1 = act[b * 6 + 1];
    const float a2 = act[b * 6 + 2];

    const float l  = C_L0 + a0;
    const float ld = l * C_D;
    const float ux = a2 / (-ld);
    const float uy = a1 / ld;
    const int   L  = (int)floorf(l / C_DS);

    float y[12];
    y[0] = 0.f; y[1] = 0.f; y[2] = 0.f;
    y[3] = 1.f; y[4] = 0.f; y[5] = 0.f;
    y[6] = 0.f; y[7] = 1.f; y[8] = 0.f;
    y[9] = 0.f; y[10] = 0.f; y[11] = 1.f;

    float* wlds = lds + wv * (64 * 14);                 // this wave's slice
    const float4* __restrict__ s = (const float4*)wlds; // 224 float4s
    const size_t wbase = (size_t)(blockIdx.x * NB + wv * 64) * 14;

#pragma unroll
    for (int seg = 0; seg < 2; ++seg) {
        for (int t = 0; t < T; ++t) {
            if (t >= 1 && t <= L) rk4_step(y, ux, uy);

            // Stage this lane's 14-float row into the wave's LDS slice.
            float2* dst = (float2*)&wlds[lane * 14];
            dst[0] = make_float2(y[0],  y[1]);
            dst[1] = make_float2(y[2],  y[3]);
            dst[2] = make_float2(y[4],  y[5]);
            dst[3] = make_float2(y[6],  y[7]);
            dst[4] = make_float2(y[8],  y[9]);
            dst[5] = make_float2(y[10], y[11]);
            dst[6] = make_float2(ux, uy);

            // Coalesced store of the wave's 64x14 chunk: 224 float4s.
            const int row = seg * T + t;
            float4* __restrict__ g =
                (float4*)(out + (size_t)row * (size_t)B * 14 + wbase);
            g[lane +   0] = s[lane +   0];
            g[lane +  64] = s[lane +  64];
            g[lane + 128] = s[lane + 128];
            if (lane < 32) g[lane + 192] = s[lane + 192];
        }
    }
}

extern "C" void kernel_launch(void* const* d_in, const int* in_sizes, int n_in,
                              void* d_out, int out_size, void* d_ws, size_t ws_size,
                              hipStream_t stream) {
    const float* act = (const float*)d_in[0];
    float* out = (float*)d_out;
    int B = in_sizes[0] / 6;               // (B, 6) actions
    int T = out_size / (2 * 14 * B);       // output is (2T, B, 14)

    int blocks = B / NB;                   // B = 262144 -> 1024 blocks
    hipLaunchKernelGGL(ode_kernel, dim3(blocks), dim3(NB), 0, stream,
                       act, out, B, T);
}